// Round 3
// baseline (575.010 us; speedup 1.0000x reference)
//
#include <hip/hip_runtime.h>
#include <stdint.h>

// CoedgeConvLayer: out = relu(f@Ws + f[ni]@Wn + f[pi]@Wp + f[mi]@Wm + sum_b)
// One gathered GEMM  M=200000, K=1024 (4 phases x 256), N=256 in bf16 MFMA.
// ws layout: [feat_bf16 102.4MB][Bpack 512KB][bias 1KB]
// R3: BM=128 (8 waves, wave=64x64) for halved B L2 traffic, depth-1 B register
//     pipeline, and T14 reg-staged gathers (issue-early/write-late) so the A
//     buffer is a SINGLE 64 KB static LDS allocation (R2's 128 KB dynamic LDS
//     suspected of killing the launch). Gathers are issued after the phase's
//     last B issue (in-order vmcnt: waits for older B never drain them) and
//     land in regs across the phase boundary; ds_write at next phase top.

#define D 256
#define BM 128

typedef __bf16 bf16x8 __attribute__((ext_vector_type(8)));
typedef float f32x4 __attribute__((ext_vector_type(4)));

static __device__ __forceinline__ uint16_t f32_to_bf16_rne(uint32_t u) {
    return (uint16_t)((u + 0x7FFFu + ((u >> 16) & 1u)) >> 16);
}

// ---------- prep: features f32 -> bf16, dense loads/stores ----------
__global__ void k_conv(const float* __restrict__ f, uint16_t* __restrict__ o, long total) {
    long base = (long)blockIdx.x * 2048;
    int t = threadIdx.x;
#pragma unroll
    for (int pass = 0; pass < 2; pass++) {
        long i = base + pass * 1024 + (long)t * 4;
        if (i + 4 > total) return;
        uint32_t v[4];
        *(uint4*)v = *(const uint4*)(f + i);
        union { uint16_t u16[4]; uint2 v2; } r;
#pragma unroll
        for (int j = 0; j < 4; j++) r.u16[j] = f32_to_bf16_rne(v[j]);
        *(uint2*)(o + i) = r.v2;
    }
}

// ---------- prep: pack W_cat [1024,256] f32 into MFMA B-fragment layout + bias ----------
// blocks 0..511: Bpack[((ksg*16+nt)*64+lane)*8+j] = bf16(W[(ksg&7)*32+(lane>>4)*8+j][nt*16+(lane&15)])
// block 512: btot = bs+bn+bp+bm
__global__ void k_pack(const float* __restrict__ Ws, const float* __restrict__ Wn,
                       const float* __restrict__ Wp, const float* __restrict__ Wm,
                       const float* __restrict__ bs, const float* __restrict__ bn,
                       const float* __restrict__ bp, const float* __restrict__ bm,
                       uint16_t* __restrict__ Bp, float* __restrict__ btot) {
    int b = blockIdx.x;
    int l = threadIdx.x;     // 0..63
    if (b == 512) {
#pragma unroll
        for (int k = 0; k < 4; k++) {
            int n = l + k * 64;
            btot[n] = bs[n] + bn[n] + bp[n] + bm[n];
        }
        return;
    }
    int ksg = b >> 4, nt = b & 15;
    int ph = ksg >> 3;
    const float* W = (ph == 0) ? Ws : (ph == 1) ? Wn : (ph == 2) ? Wp : Wm;
    int kl = (ksg & 7) * 32 + (l >> 4) * 8;
    int n  = nt * 16 + (l & 15);
    uint16_t* dst = Bp + ((size_t)b * 64 + l) * 8;
#pragma unroll
    for (int j = 0; j < 8; j++) {
        uint32_t u = __builtin_bit_cast(uint32_t, W[(size_t)(kl + j) * D + n]);
        dst[j] = f32_to_bf16_rne(u);
    }
}

// ---------- main gathered GEMM ----------
// 512 threads = 8 waves in 2x4 grid (wr=w>>2, wc=w&3); wave tile 64 rows x 64 cols.
// Single 64 KB static LDS A-buffer. Per phase (K=256):
//   [gathers for this phase arrived in regs during previous phase]
//   barrier; ds_write staged regs (write-side XOR swizzle); lgkmcnt(0); barrier;
//   compute ks0..7 with Ba/Bb register rotation on B (L2 latency hidden);
//   after last B issue (ks7): issue next phase's 8 gather loads -> regs
//   (newest vmem ops; waits for older B fragments never drain them).
__global__ __launch_bounds__(512, 2) void k_gemm(
    const uint16_t* __restrict__ fb,
    const int* __restrict__ ni, const int* __restrict__ pi, const int* __restrict__ mi,
    const uint16_t* __restrict__ Bp, const float* __restrict__ btot,
    float* __restrict__ out, int nrows)
{
    __shared__ uint16_t As[BM * D];          // 64 KB static, single buffer
    const int t  = threadIdx.x;
    const int w  = t >> 6;
    const int l  = t & 63;
    const int ml = l & 15;
    const int q  = l >> 4;
    const int wr = w >> 2;
    const int wc = w & 3;
    const int m0 = blockIdx.x * BM;

    f32x4 acc[4][4] = {};                    // 64 VGPR

    const int rpar = w * 16 + (l >> 5);      // staging rows: wave w fills [w*16, w*16+16)
    const int cs   = l & 31;                 // 16B-chunk slot within row (linear fetch)

    // Per-lane gather byte offsets (all 4 phases; indices loaded once) + LDS
    // write offsets (write-side swizzle: global chunk cs -> LDS slot cs^(r&7)).
    uint32_t off0[8], off1[8], off2[8], off3[8], loff[8];
#pragma unroll
    for (int e = 0; e < 8; e++) {
        int r = rpar + e * 2;
        int rowg = m0 + r; if (rowg >= nrows) rowg = nrows - 1;
        uint32_t co = (uint32_t)(cs * 16);
        off0[e] = (uint32_t)rowg * (D * 2) + co;
        off1[e] = (uint32_t)ni[rowg] * (D * 2) + co;
        off2[e] = (uint32_t)pi[rowg] * (D * 2) + co;
        off3[e] = (uint32_t)mi[rowg] * (D * 2) + co;
        loff[e] = (uint32_t)r * (D * 2) + (uint32_t)((cs ^ (r & 7)) * 16);
    }

    uint4 st[8];                             // staged gather data (32 VGPR)

#define STAGE_LOAD(OFFA) do { \
        _Pragma("unroll") \
        for (int e = 0; e < 8; e++) \
            st[e] = *(const uint4*)((const char*)fb + (OFFA)[e]); \
    } while (0)

#define STAGE_WRITE() do { \
        _Pragma("unroll") \
        for (int e = 0; e < 8; e++) \
            *(uint4*)((char*)As + loff[e]) = st[e]; \
    } while (0)

#define LOADB(DST, KS) do { \
        _Pragma("unroll") \
        for (int j = 0; j < 4; j++) \
            (DST)[j] = *(const bf16x8*)(bb + ((KS) * 16 + j) * 512); \
    } while (0)

#define MM(BREG, KS) do { \
        _Pragma("unroll") \
        for (int mt = 0; mt < 4; mt++) { \
            int r  = wr * 64 + mt * 16 + ml; \
            int ch = ((KS) * 4 + q) ^ (r & 7);            /* read-side swizzle */ \
            bf16x8 afr = *(const bf16x8*)&As[r * D + ch * 8]; \
            _Pragma("unroll") \
            for (int j = 0; j < 4; j++) \
                acc[mt][j] = __builtin_amdgcn_mfma_f32_16x16x32_bf16( \
                    afr, (BREG)[j], acc[mt][j], 0, 0, 0); \
        } \
    } while (0)

    // Phase: barrier (all waves done reading As) -> write staged regs ->
    // lgkmcnt(0) + barrier (writes visible) -> compute.
#define PHASE(P, OFFNEXT, LAST) do { \
        __builtin_amdgcn_s_barrier(); \
        __builtin_amdgcn_sched_barrier(0); \
        STAGE_WRITE(); \
        asm volatile("s_waitcnt lgkmcnt(0)" ::: "memory"); \
        __builtin_amdgcn_s_barrier(); \
        __builtin_amdgcn_sched_barrier(0); \
        const uint16_t* bb = Bp + (((size_t)(P) * 128 + wc * 4) * 64 + l) * 8; \
        bf16x8 Ba[4], Bb[4]; \
        LOADB(Ba, 0); \
        LOADB(Bb, 1); MM(Ba, 0); \
        LOADB(Ba, 2); MM(Bb, 1); \
        LOADB(Bb, 3); MM(Ba, 2); \
        LOADB(Ba, 4); MM(Bb, 3); \
        LOADB(Bb, 5); MM(Ba, 4); \
        LOADB(Ba, 6); MM(Bb, 5); \
        LOADB(Bb, 7); \
        if (!(LAST)) { \
            __builtin_amdgcn_sched_barrier(0); \
            STAGE_LOAD(OFFNEXT); \
            __builtin_amdgcn_sched_barrier(0); \
        } \
        MM(Ba, 6); \
        MM(Bb, 7); \
    } while (0)

    STAGE_LOAD(off0);
    PHASE(0, off1, 0);
    PHASE(1, off2, 0);
    PHASE(2, off3, 0);
    PHASE(3, off0, 1);

#undef PHASE
#undef MM
#undef LOADB
#undef STAGE_WRITE
#undef STAGE_LOAD

    // epilogue: C/D layout col=lane&15, row=(lane>>4)*4+reg  [m89-verified]
#pragma unroll
    for (int j = 0; j < 4; j++) {
        int n = (wc * 4 + j) * 16 + ml;
        float bv = btot[n];
#pragma unroll
        for (int mt = 0; mt < 4; mt++) {
#pragma unroll
            for (int rg = 0; rg < 4; rg++) {
                int row = m0 + wr * 64 + mt * 16 + q * 4 + rg;
                if (row < nrows) {
                    float v = acc[mt][j][rg] + bv;
                    out[(size_t)row * D + n] = v > 0.f ? v : 0.f;
                }
            }
        }
    }
}

// ---------- fallback (ws too small): naive fp32, correct but slow ----------
__global__ void k_naive(const float* __restrict__ f,
                        const int* __restrict__ ni, const int* __restrict__ pi,
                        const int* __restrict__ mi,
                        const float* __restrict__ Ws, const float* __restrict__ bs,
                        const float* __restrict__ Wn, const float* __restrict__ bn,
                        const float* __restrict__ Wp, const float* __restrict__ bp,
                        const float* __restrict__ Wm, const float* __restrict__ bm,
                        float* __restrict__ out) {
    int row = blockIdx.x, n = threadIdx.x;
    const float* f0 = f + (size_t)row * D;
    const float* f1 = f + (size_t)ni[row] * D;
    const float* f2 = f + (size_t)pi[row] * D;
    const float* f3 = f + (size_t)mi[row] * D;
    float s = bs[n] + bn[n] + bp[n] + bm[n];
    for (int k = 0; k < D; k++)
        s += f0[k] * Ws[k * D + n] + f1[k] * Wn[k * D + n] +
             f2[k] * Wp[k * D + n] + f3[k] * Wm[k * D + n];
    out[(size_t)row * D + n] = s > 0.f ? s : 0.f;
}

extern "C" void kernel_launch(void* const* d_in, const int* in_sizes, int n_in,
                              void* d_out, int out_size, void* d_ws, size_t ws_size,
                              hipStream_t stream) {
    const float* feat = (const float*)d_in[0];
    const int*   ni   = (const int*)d_in[1];
    const int*   pi   = (const int*)d_in[2];
    const int*   mi   = (const int*)d_in[3];
    const float* Ws   = (const float*)d_in[4];
    const float* bs   = (const float*)d_in[5];
    const float* Wn   = (const float*)d_in[6];
    const float* bn   = (const float*)d_in[7];
    const float* Wp   = (const float*)d_in[8];
    const float* bp   = (const float*)d_in[9];
    const float* Wm   = (const float*)d_in[10];
    const float* bm   = (const float*)d_in[11];
    float* out = (float*)d_out;

    int nrows = in_sizes[1];
    size_t feat_elems = (size_t)nrows * D;
    size_t fb_bytes   = feat_elems * 2;
    size_t bp_off     = fb_bytes;                 // 16B aligned (nrows*512)
    size_t bias_off   = bp_off + (size_t)1024 * D * 2;
    size_t need       = bias_off + (size_t)D * 4;

    if (ws_size < need) {
        k_naive<<<nrows, D, 0, stream>>>(feat, ni, pi, mi, Ws, bs, Wn, bn, Wp, bp, Wm, bm, out);
        return;
    }

    uint16_t* fbuf = (uint16_t*)d_ws;
    uint16_t* Bpk  = (uint16_t*)((char*)d_ws + bp_off);
    float*    btot = (float*)((char*)d_ws + bias_off);

    long total = (long)feat_elems;
    int cblocks = (int)((total + 2047) / 2048);
    k_conv<<<cblocks, 256, 0, stream>>>(feat, fbuf, total);
    k_pack<<<513, 64, 0, stream>>>(Ws, Wn, Wp, Wm, bs, bn, bp, bm, Bpk, btot);
    k_gemm<<<(nrows + BM - 1) / BM, 512, 0, stream>>>(fbuf, ni, pi, mi, Bpk, btot, out, nrows);
}